// Round 13
// baseline (6779.754 us; speedup 1.0000x reference)
//
#include <hip/hip_runtime.h>
#include <math.h>

#define TSTEPS 512
#define CH 16
#define NCHUNK 32
#define EPSR 1e-8f

// ws layout in ushort units (all f16 except OWIN/OWC=bf16, OBC=f32)
#define OHH   0u        // uint4[jp=128][t=256]       {g0(j0,j1) g1 g2 g3} Whh
#define OSUB  262144u   // uint4[s=4][jq=16][d=64][4] {ih(j01) ih(j23) hh(j01) hh(j23)} x g0..3
#define OQK   393216u   // uint4[jq=64][d=64]         {q(j01) q(j23) k(j01) k(j23)}
#define OV    425984u   // uint4[jq2=32][d=64]        {v(8 consecutive j)}
#define OWO   442368u   // uint4[jq2=32][t=256]       {wo(8 consecutive j)}
#define OWP   507904u   // uint4[jq2=8][t=256]        {wp(8 consecutive j)}
#define OWIN  524288u   // bf16 [k=128][t=256]        W_in
#define NPACK1 557056u
#define OWC   557056u   // bf16 [k=128][t=256][g=4]   Wc = W_in @ Wih
#define OBC   688128u   // f32[1024] bc = b_in@Wih + bih

typedef __fp16 h2_t __attribute__((ext_vector_type(2)));

__device__ __forceinline__ float dot2(unsigned int w, unsigned int a, float acc) {
    union U { unsigned int u; h2_t h; };
    U cw; cw.u = w; U ca; ca.u = a;
    return __builtin_amdgcn_fdot2(cw.h, ca.h, acc, false);
}
__device__ __forceinline__ unsigned int pk2f(float a, float b) {
    union { h2_t h; unsigned int u; } c;
    c.h = __builtin_amdgcn_cvt_pkrtz(a, b);
    return c.u;
}
__device__ __forceinline__ float bfu(unsigned int v) {
    union { unsigned int i; float f; } c; c.i = v; return c.f;
}
__device__ __forceinline__ float sigmoidf_(float v) { return 1.0f / (1.0f + expf(-v)); }
__device__ __forceinline__ unsigned short f2bf(float f) {
    unsigned int u = __float_as_uint(f);
    return (unsigned short)((u + 0x7fffu + ((u >> 16) & 1u)) >> 16);
}

extern "C" __global__ void pack_w(const float* __restrict__ Whh,
    const float* __restrict__ sWih, const float* __restrict__ sWhh,
    const float* __restrict__ Wq, const float* __restrict__ Wk, const float* __restrict__ Wv,
    const float* __restrict__ Wo, const float* __restrict__ Wp,
    const float* __restrict__ W_in, unsigned short* __restrict__ ws)
{
    unsigned e = blockIdx.x * 256u + threadIdx.x;
    if (e >= NPACK1) return;
    float v; bool isbf = false;
    if (e < OSUB) {
        unsigned idx = e >> 3, sl = e & 7u;
        unsigned jp = idx >> 8, t = idx & 255u, g = sl >> 1, ee = sl & 1u;
        v = Whh[(2u * jp + ee) * 1024u + g * 256u + t];
    } else if (e < OQK) {
        unsigned r = e - OSUB, idx = r >> 3, sl = r & 7u;
        unsigned q4 = idx & 3u, d = (idx >> 2) & 63u, jq = (idx >> 8) & 15u, s = idx >> 12;
        unsigned g = sl >> 1, ee = sl & 1u;
        unsigned j = jq * 4u + (q4 & 1u) * 2u + ee;
        const float* src = (q4 >> 1) ? sWhh : sWih;
        v = src[(s * 64u + j) * 256u + g * 64u + d];
    } else if (e < OV) {
        unsigned r = e - OQK, idx = r >> 3, sl = r & 7u;
        unsigned d = idx & 63u, jq = idx >> 6;
        unsigned j = jq * 4u + (sl & 3u);
        v = ((sl >> 2) ? Wk : Wq)[j * 64u + d];
    } else if (e < OWO) {
        unsigned r = e - OV, idx = r >> 3, sl = r & 7u;
        unsigned d = idx & 63u, jq2 = idx >> 6;
        unsigned j = jq2 * 8u + sl;
        v = Wv[j * 64u + d];
    } else if (e < OWP) {
        unsigned r = e - OWO, idx = r >> 3, sl = r & 7u;
        unsigned t = idx & 255u, jq2 = idx >> 8;
        unsigned j = jq2 * 8u + sl;
        v = Wo[j * 256u + t];
    } else if (e < OWIN) {
        unsigned r = e - OWP, idx = r >> 3, sl = r & 7u;
        unsigned t = idx & 255u, jq2 = idx >> 8;
        unsigned j = jq2 * 8u + sl;
        v = Wp[j * 256u + t];
    } else {
        v = W_in[e - OWIN]; isbf = true;
    }
    if (isbf) ws[e] = f2bf(v);
    else { union { __fp16 h; unsigned short s; } c; c.h = (__fp16)v; ws[e] = c.s; }
}

extern "C" __global__ void compute_wc(const float* __restrict__ W_in,
    const float* __restrict__ Wih, const float* __restrict__ b_in,
    const float* __restrict__ bih, unsigned short* __restrict__ ws)
{
    unsigned e = blockIdx.x * 256u + threadIdx.x;
    if (e < 131072u) {
        unsigned k = e >> 10, n = e & 1023u;
        float acc = 0.f;
        for (int j = 0; j < 256; ++j) acc += W_in[k * 256 + j] * Wih[j * 1024 + n];
        unsigned t = n & 255u, g = n >> 8;
        ws[OWC + k * 1024 + t * 4 + g] = f2bf(acc);
    } else if (e < 132096u) {
        unsigned n = e - 131072u;
        float acc = bih[n];
        for (int j = 0; j < 256; ++j) acc += b_in[j] * Wih[j * 1024 + n];
        float* bc = (float*)(ws + OBC);
        bc[n] = acc;
    }
}

extern "C" __global__ __launch_bounds__(512)
void xlstm_seq(const float* __restrict__ x, const float* __restrict__ b_in,
               const float* __restrict__ bq, const float* __restrict__ bk, const float* __restrict__ bv,
               const float* __restrict__ Wi, const float* __restrict__ bi,
               const float* __restrict__ Wf, const float* __restrict__ bf,
               const float* __restrict__ bo, const float* __restrict__ bp,
               const float* __restrict__ sbih, const float* __restrict__ sfb,
               const float* __restrict__ aW1, const float* __restrict__ ab1,
               const float* __restrict__ aW2, const float* __restrict__ ab2,
               const float* __restrict__ lng, const float* __restrict__ lnb,
               const unsigned short* __restrict__ pk,
               float* __restrict__ out)
{
    const int u = threadIdx.x;          // 0..511
    const int b = blockIdx.x;
    const int t256 = u & 255;
    const int half = u >> 8;

    __shared__ float g_chunk[CH][1024];
    __shared__ float xt_chunk[CH][256];
    __shared__ __align__(16) float xT[128][20];
    __shared__ __align__(16) float x1_l[256], hs_l[256];
    __shared__ float opre_l[256];
    __shared__ float psum[4][520];
    __shared__ float qb[64], kb[64], vb[64];
    __shared__ float Cm[64 * 65];
    __shared__ float sc_l[16];
    __shared__ __align__(16) float Wi_l[256], Wf_l[256];
    __shared__ float sbih_l[1024], bc_l[1024];
    __shared__ float b_in_l[256], bo_l[256], bp_l[256], sfb_l[256], bqkv_l[192];
    __shared__ __align__(16) unsigned int h0p[128], x1p[128], x2p[128], hsp[128], htp[32];

    // ---- init ----
    {
        const float* bcg = (const float*)(pk + OBC);
        for (int e = u; e < 1024; e += 512) { sbih_l[e] = sbih[e]; bc_l[e] = bcg[e]; }
    }
    if (u < 256) {
        Wi_l[u] = Wi[u]; Wf_l[u] = Wf[u];
        b_in_l[u] = b_in[u]; bo_l[u] = bo[u]; bp_l[u] = bp[u]; sfb_l[u] = sfb[u];
        hs_l[u] = 0.f;
    }
    if (u < 192) bqkv_l[u] = (u < 64) ? bq[u] : (u < 128) ? bk[u - 64] : bv[u - 128];
    if (u < 128) { h0p[u] = 0u; hsp[u] = 0u; }
    if (u == 0) { sc_l[10] = bi[0]; sc_l[11] = bf[0]; }
    for (int e = u; e < 64 * 65; e += 512) Cm[e] = 0.f;
    float c0 = 0.f, n0 = 1.f, cs = 0.f, ns = 1.f, n1 = 1.f;
    __syncthreads();

    const uint4* pwhh = reinterpret_cast<const uint4*>(pk + OHH) + t256;        // + jp*256
    const uint4* psub = reinterpret_cast<const uint4*>(pk + OSUB)
                        + ((size_t)((t256 >> 6) * 1024 + (t256 & 63))) * 4;     // + jq*256
    const uint4* pqk = reinterpret_cast<const uint4*>(pk + OQK) + (u & 63);     // + jq*64
    const uint4* pv4 = reinterpret_cast<const uint4*>(pk + OV) + (u & 63);      // + jq2*64
    const uint4* pwoB = reinterpret_cast<const uint4*>(pk + OWO);               // [jq2*256 + t]
    const uint4* pwpB = reinterpret_cast<const uint4*>(pk + OWP);               // [jq2*256 + t]
    const unsigned short* pwin = pk + OWIN + t256;
    const uint2* pwc = reinterpret_cast<const uint2*>(pk + OWC) + t256;
    const float* xrow = x + (size_t)b * TSTEPS * 128;

    for (int cc = 0; cc < NCHUNK; ++cc) {
        // ---- Phase A: load x chunk, transpose ----
        {
            float4 xv4 = *reinterpret_cast<const float4*>(xrow + cc * (CH * 128) + u * 4);
            int m = u >> 5, k0 = (u * 4) & 127;
            xT[k0][m] = xv4.x; xT[k0 + 1][m] = xv4.y; xT[k0 + 2][m] = xv4.z; xT[k0 + 3][m] = xv4.w;
        }
        __syncthreads();

        // ---- Phase B: xt = x@W_in + b_in ; g_ih = x@Wc + bc ----
        {
            const int m0 = half * 8;
            float xtacc[8], gacc[4][8];
            {
                float bi_ = b_in_l[t256];
                #pragma unroll
                for (int e = 0; e < 8; ++e) xtacc[e] = bi_;
                #pragma unroll
                for (int g = 0; g < 4; ++g) {
                    float bcv = bc_l[g * 256 + t256];
                    #pragma unroll
                    for (int e = 0; e < 8; ++e) gacc[g][e] = bcv;
                }
            }
            #pragma unroll 4
            for (int k = 0; k < 128; ++k) {
                float wv = bfu((unsigned)pwin[k * 256] << 16);
                uint2 wg = pwc[k * 256];
                float w0 = bfu(wg.x << 16), w1 = bfu(wg.x & 0xffff0000u);
                float w2 = bfu(wg.y << 16), w3 = bfu(wg.y & 0xffff0000u);
                float4 a  = *reinterpret_cast<const float4*>(&xT[k][m0]);
                float4 b4 = *reinterpret_cast<const float4*>(&xT[k][m0 + 4]);
                #pragma unroll
                for (int e = 0; e < 8; ++e) {
                    float xv = (e == 0) ? a.x : (e == 1) ? a.y : (e == 2) ? a.z : (e == 3) ? a.w
                             : (e == 4) ? b4.x : (e == 5) ? b4.y : (e == 6) ? b4.z : b4.w;
                    xtacc[e]   += xv * wv;
                    gacc[0][e] += xv * w0;
                    gacc[1][e] += xv * w1;
                    gacc[2][e] += xv * w2;
                    gacc[3][e] += xv * w3;
                }
            }
            #pragma unroll
            for (int e = 0; e < 8; ++e) {
                xt_chunk[m0 + e][t256] = xtacc[e];
                g_chunk[m0 + e][t256]       = gacc[0][e];
                g_chunk[m0 + e][256 + t256] = gacc[1][e];
                g_chunk[m0 + e][512 + t256] = gacc[2][e];
                g_chunk[m0 + e][768 + t256] = gacc[3][e];
            }
        }
        __syncthreads();

        for (int st = 0; st < CH; ++st) {
            // ---- S3: hh-half of layer-0 gates via fdot2 (split-K 2) ----
            {
                float g0 = 0.f, g1 = 0.f, g2 = 0.f, g3 = 0.f;
                const int jp0 = half * 64;
                #pragma unroll 4
                for (int q = 0; q < 16; ++q) {
                    uint4 hp4 = *reinterpret_cast<const uint4*>(&h0p[jp0 + q * 4]);
                    #pragma unroll
                    for (int e = 0; e < 4; ++e) {
                        uint4 wk = pwhh[(size_t)(jp0 + q * 4 + e) * 256];
                        unsigned int hp = (e == 0) ? hp4.x : (e == 1) ? hp4.y : (e == 2) ? hp4.z : hp4.w;
                        g0 = dot2(wk.x, hp, g0);
                        g1 = dot2(wk.y, hp, g1);
                        g2 = dot2(wk.z, hp, g2);
                        g3 = dot2(wk.w, hp, g3);
                    }
                }
                psum[0][u] = g0; psum[1][u] = g1; psum[2][u] = g2; psum[3][u] = g3;
            }
            __syncthreads();
            if (u < 256) {
                float G0 = g_chunk[st][u]       + psum[0][u] + psum[0][256 + u];
                float G1 = g_chunk[st][256 + u] + psum[1][u] + psum[1][256 + u];
                float G2 = g_chunk[st][512 + u] + psum[2][u] + psum[2][256 + u];
                float G3 = g_chunk[st][768 + u] + psum[3][u] + psum[3][256 + u];
                float i0 = expf(G0), f0 = sigmoidf_(G1), o0 = sigmoidf_(G2);
                float cn = f0 * c0 + i0 * tanhf(G3);
                float nn = f0 * n0 + i0;
                c0 = cn; n0 = nn;
                float h0n = o0 * tanhf(cn / (nn + EPSR));
                float x1v = h0n + xt_chunk[st][u];
                x1_l[u] = x1v;
                float h0o = __shfl_xor(h0n, 1);
                float x1o = __shfl_xor(x1v, 1);
                if (!(u & 1)) { h0p[u >> 1] = pk2f(h0n, h0o); x1p[u >> 1] = pk2f(x1v, x1o); }
            }
            __syncthreads();

            // ---- S4: qkv (waves 0-3) | i/f (waves 4-5) + Wo full-K (waves 4-7) ----
            if (u < 256) {
                const int jq0 = (u >> 6) * 16;      // 16 jq's = 8 jq2's
                float pq = 0.f, pkk = 0.f, pvv = 0.f;
                #pragma unroll 4
                for (int q2 = 0; q2 < 8; ++q2) {
                    int jq = jq0 + q2 * 2;
                    uint4 wqk0 = pqk[(size_t)jq * 64];
                    uint4 wqk1 = pqk[(size_t)(jq + 1) * 64];
                    uint4 wv4 = pv4[(size_t)((jq0 >> 1) + q2) * 64];
                    uint4 ap4 = *reinterpret_cast<const uint4*>(&x1p[jq * 2]);
                    pq  = dot2(wqk0.x, ap4.x, pq);  pq  = dot2(wqk0.y, ap4.y, pq);
                    pq  = dot2(wqk1.x, ap4.z, pq);  pq  = dot2(wqk1.y, ap4.w, pq);
                    pkk = dot2(wqk0.z, ap4.x, pkk); pkk = dot2(wqk0.w, ap4.y, pkk);
                    pkk = dot2(wqk1.z, ap4.z, pkk); pkk = dot2(wqk1.w, ap4.w, pkk);
                    pvv = dot2(wv4.x, ap4.x, pvv);  pvv = dot2(wv4.y, ap4.y, pvv);
                    pvv = dot2(wv4.z, ap4.z, pvv);  pvv = dot2(wv4.w, ap4.w, pvv);
                }
                psum[0][u] = pq; psum[1][u] = pkk; psum[2][u] = pvv;
            } else {
                if (u < 384) {
                    const float* Wl = (u < 320) ? Wi_l : Wf_l;
                    int j0 = (u & 63) * 4;
                    float4 xv = *reinterpret_cast<const float4*>(&x1_l[j0]);
                    float4 wv = *reinterpret_cast<const float4*>(&Wl[j0]);
                    float p = xv.x * wv.x + xv.y * wv.y + xv.z * wv.z + xv.w * wv.w;
                    #pragma unroll
                    for (int off = 32; off > 0; off >>= 1) p += __shfl_down(p, off);
                    if ((u & 63) == 0) sc_l[(u < 320) ? 8 : 9] = p;
                }
                // Wo full-K, one column per thread: waves 4-5 -> cols 0..127, waves 6-7 -> 128..255
                int c = (u < 384) ? (u - 256) : (u - 384 + 128);
                float p = bo_l[c];
                #pragma unroll 4
                for (int q2 = 0; q2 < 32; ++q2) {
                    uint4 w4 = pwoB[(size_t)q2 * 256 + c];
                    uint4 ap4 = *reinterpret_cast<const uint4*>(&x1p[q2 * 4]);
                    p = dot2(w4.x, ap4.x, p); p = dot2(w4.y, ap4.y, p);
                    p = dot2(w4.z, ap4.z, p); p = dot2(w4.w, ap4.w, p);
                }
                opre_l[c] = p;
            }
            __syncthreads();
            {
                int lane = u & 63;
                if (u < 64)        qb[u]    = bqkv_l[u]          + psum[0][u] + psum[0][64 + u] + psum[0][128 + u] + psum[0][192 + u];
                else if (u < 128)  kb[lane] = bqkv_l[64 + lane]  + psum[1][lane] + psum[1][64 + lane] + psum[1][128 + lane] + psum[1][192 + lane];
                else if (u < 192)  vb[lane] = bqkv_l[128 + lane] + psum[2][lane] + psum[2][64 + lane] + psum[2][128 + lane] + psum[2][192 + lane];
                else if (u == 192) sc_l[0] = expf(sc_l[10] + sc_l[8]);
                else if (u == 193) sc_l[1] = sigmoidf_(sc_l[11] + sc_l[9]);
            }
            __syncthreads();

            // ---- S5: C update + fused Cq + htp pack (short phase) ----
            float i1 = sc_l[0], f1 = sc_l[1];
            n1 = f1 * n1 + i1;
            {
                int r = u >> 3, ci = (u & 7) * 8;
                float vi = i1 * vb[r];
                float cqp = 0.f;
                #pragma unroll
                for (int e = 0; e < 8; ++e) {
                    int c = ci + e;
                    float cmv = f1 * Cm[r * 65 + c] + vi * kb[c];
                    Cm[r * 65 + c] = cmv;
                    cqp += cmv * qb[c];
                }
                cqp += __shfl_down(cqp, 4);
                cqp += __shfl_down(cqp, 2);
                cqp += __shfl_down(cqp, 1);
                float htv = cqp / (n1 + EPSR);
                float hto = __shfl_xor(htv, 8);
                if ((u & 15) == 0) htp[u >> 4] = pk2f(htv, hto);
            }
            __syncthreads();

            // ---- S6 merged: opre + full-K Wp + x2 (u<256 only) ----
            if (u < 256) {
                float pp = bp_l[u];
                #pragma unroll
                for (int q2 = 0; q2 < 8; ++q2) {
                    uint4 w4 = pwpB[(size_t)q2 * 256 + u];
                    uint4 ap4 = *reinterpret_cast<const uint4*>(&htp[q2 * 4]);
                    pp = dot2(w4.x, ap4.x, pp); pp = dot2(w4.y, ap4.y, pp);
                    pp = dot2(w4.z, ap4.z, pp); pp = dot2(w4.w, ap4.w, pp);
                }
                float h1 = sigmoidf_(opre_l[u]) * tanhf(pp);
                float x2v = h1 + x1_l[u];
                float x2o = __shfl_xor(x2v, 1);
                if (!(u & 1)) x2p[u >> 1] = pk2f(x2v, x2o);
            }
            __syncthreads();

            // ---- S8: subspace gates via fdot2 (split-K 2) ----
            {
                const int sbase = (t256 >> 6) * 32;
                const int jqb = half * 8;
                float g0 = 0.f, g1 = 0.f, g2 = 0.f, g3 = 0.f;
                #pragma unroll 2
                for (int q = 0; q < 8; ++q) {
                    int jq = jqb + q;
                    const uint4* pp4 = psub + (size_t)jq * 256;
                    uint4 wih0 = pp4[0], wih1 = pp4[1], whh0 = pp4[2], whh1 = pp4[3];
                    uint2 xp = *reinterpret_cast<const uint2*>(&x2p[sbase + jq * 2]);
                    uint2 hp = *reinterpret_cast<const uint2*>(&hsp[sbase + jq * 2]);
                    g0 = dot2(wih0.x, xp.x, g0); g0 = dot2(wih1.x, xp.y, g0);
                    g0 = dot2(whh0.x, hp.x, g0); g0 = dot2(whh1.x, hp.y, g0);
                    g1 = dot2(wih0.y, xp.x, g1); g1 = dot2(wih1.y, xp.y, g1);
                    g1 = dot2(whh0.y, hp.x, g1); g1 = dot2(whh1.y, hp.y, g1);
                    g2 = dot2(wih0.z, xp.x, g2); g2 = dot2(wih1.z, xp.y, g2);
                    g2 = dot2(whh0.z, hp.x, g2); g2 = dot2(whh1.z, hp.y, g2);
                    g3 = dot2(wih0.w, xp.x, g3); g3 = dot2(wih1.w, xp.y, g3);
                    g3 = dot2(whh0.w, hp.x, g3); g3 = dot2(whh1.w, hp.y, g3);
                }
                psum[0][u] = g0; psum[1][u] = g1; psum[2][u] = g2; psum[3][u] = g3;
            }
            __syncthreads();
            if (u < 256) {
                int s = u >> 6, dd = u & 63;
                float sg0 = psum[0][u] + psum[0][256 + u] + sbih_l[s * 256 + dd];
                float sg1 = psum[1][u] + psum[1][256 + u] + sbih_l[s * 256 + 64 + dd];
                float sg2 = psum[2][u] + psum[2][256 + u] + sbih_l[s * 256 + 128 + dd];
                float sg3 = psum[3][u] + psum[3][256 + u] + sbih_l[s * 256 + 192 + dd];
                float si = expf(sg0);
                float sf = sigmoidf_(sg1 + sfb_l[u]);
                float so = sigmoidf_(sg2);
                float csn = sf * cs + si * tanhf(sg3);
                float nsn = sf * ns + si;
                cs = csn; ns = nsn;
                float hsn = so * tanhf(csn / (nsn + EPSR));
                hs_l[u] = hsn;
                float hso = __shfl_xor(hsn, 1);
                if (!(u & 1)) hsp[u >> 1] = pk2f(hsn, hso);
            }
            __syncthreads();
        }
    }

    // ---- epilogue: attention fusion + layernorm ----
    if (u < 256) {
        int s = u >> 6, dd = u & 63;
        float av = ab1[dd];
        for (int j = 0; j < 64; ++j) av += hs_l[s * 64 + j] * aW1[j * 64 + dd];
        float contrib = tanhf(av) * aW2[dd];
        #pragma unroll
        for (int off = 32; off > 0; off >>= 1) contrib += __shfl_down(contrib, off);
        if (dd == 0) sc_l[4 + s] = contrib + ab2[0];
    }
    __syncthreads();
    if (u < 256) {
        float a0 = sc_l[4], a1 = sc_l[5], a2 = sc_l[6], a3 = sc_l[7];
        float m = fmaxf(fmaxf(a0, a1), fmaxf(a2, a3));
        float e0 = expf(a0 - m), e1 = expf(a1 - m), e2 = expf(a2 - m), e3 = expf(a3 - m);
        float inv = 1.f / (e0 + e1 + e2 + e3);
        int dd = u & 63;
        psum[0][u] = (e0 * hs_l[dd] + e1 * hs_l[64 + dd] + e2 * hs_l[128 + dd] + e3 * hs_l[192 + dd]) * inv;
    }
    __syncthreads();
    if (u < 256) {
        float mu = 0.f;
        for (int j = 0; j < 256; ++j) mu += psum[0][j];
        mu *= (1.0f / 256.0f);
        float var = 0.f;
        for (int j = 0; j < 256; ++j) { float dv = psum[0][j] - mu; var += dv * dv; }
        var *= (1.0f / 256.0f);
        out[b * 256 + u] = (psum[0][u] - mu) / sqrtf(var + 1e-5f) * lng[u] + lnb[u];
    }
}

extern "C" void kernel_launch(void* const* d_in, const int* in_sizes, int n_in,
                              void* d_out, int out_size, void* d_ws, size_t ws_size,
                              hipStream_t stream) {
    (void)in_sizes; (void)n_in; (void)out_size; (void)ws_size;
    const float* x     = (const float*)d_in[0];
    const float* W_in  = (const float*)d_in[1];
    const float* b_in  = (const float*)d_in[2];
    const float* Wih   = (const float*)d_in[3];
    const float* bih   = (const float*)d_in[4];
    const float* Whh   = (const float*)d_in[5];
    const float* Wq    = (const float*)d_in[6];
    const float* bq    = (const float*)d_in[7];
    const float* Wk    = (const float*)d_in[8];
    const float* bk    = (const float*)d_in[9];
    const float* Wv    = (const float*)d_in[10];
    const float* bv    = (const float*)d_in[11];
    const float* Wi    = (const float*)d_in[12];
    const float* bi    = (const float*)d_in[13];
    const float* Wf    = (const float*)d_in[14];
    const float* bf    = (const float*)d_in[15];
    const float* Wo    = (const float*)d_in[16];
    const float* bo    = (const float*)d_in[17];
    const float* Wp    = (const float*)d_in[18];
    const float* bp    = (const float*)d_in[19];
    const float* sWih  = (const float*)d_in[20];
    const float* sbih  = (const float*)d_in[21];
    const float* sWhh  = (const float*)d_in[22];
    const float* sfb   = (const float*)d_in[23];
    const float* aW1   = (const float*)d_in[24];
    const float* ab1   = (const float*)d_in[25];
    const float* aW2   = (const float*)d_in[26];
    const float* ab2   = (const float*)d_in[27];
    const float* lng   = (const float*)d_in[28];
    const float* lnb   = (const float*)d_in[29];
    float* out = (float*)d_out;
    unsigned short* ws = (unsigned short*)d_ws;

    pack_w<<<dim3((NPACK1 + 255u) / 256u), dim3(256), 0, stream>>>(
        Whh, sWih, sWhh, Wq, Wk, Wv, Wo, Wp, W_in, ws);
    compute_wc<<<dim3(517), dim3(256), 0, stream>>>(W_in, Wih, b_in, bih, ws);

    xlstm_seq<<<dim3(256), dim3(512), 0, stream>>>(
        x, b_in, bq, bk, bv, Wi, bi, Wf, bf, bo, bp,
        sbih, sfb, aW1, ab1, aW2, ab2, lng, lnb, ws, out);
}

// Round 14
// 6549.098 us; speedup vs baseline: 1.0352x; 1.0352x over previous
//
#include <hip/hip_runtime.h>
#include <math.h>

#define TSTEPS 512
#define CH 16
#define NCHUNK 32
#define EPSR 1e-8f

// ws layout in ushort units (all f16 except OWIN/OWC=bf16, OBC=f32)
#define OHH   0u        // uint4[jp=128][t=256]       {g0(j0,j1) g1 g2 g3} Whh
#define OSUB  262144u   // uint4[s=4][jq=16][d=64][4] {ih(j01) ih(j23) hh(j01) hh(j23)} x g0..3
#define OQK   393216u   // uint4[jq=64][d=64]         {q(j01) q(j23) k(j01) k(j23)}
#define OV    425984u   // uint4[jq2=32][d=64]        {v(8 consecutive j)}
#define OWO   442368u   // uint4[jq2=32][t=256]       {wo(8 consecutive j)}
#define OWP   507904u   // uint4[jq2=8][t=256]        {wp(8 consecutive j)}
#define OWIN  524288u   // bf16 [k=128][t=256]        W_in
#define NPACK1 557056u
#define OWC   557056u   // bf16 [k=128][t=256][g=4]   Wc = W_in @ Wih
#define OBC   688128u   // f32[1024] bc = b_in@Wih + bih

typedef __fp16 h2_t __attribute__((ext_vector_type(2)));

__device__ __forceinline__ float dot2(unsigned int w, unsigned int a, float acc) {
    union U { unsigned int u; h2_t h; };
    U cw; cw.u = w; U ca; ca.u = a;
    return __builtin_amdgcn_fdot2(cw.h, ca.h, acc, false);
}
__device__ __forceinline__ unsigned int pk2f(float a, float b) {
    union { h2_t h; unsigned int u; } c;
    c.h = __builtin_amdgcn_cvt_pkrtz(a, b);
    return c.u;
}
__device__ __forceinline__ float bfu(unsigned int v) {
    union { unsigned int i; float f; } c; c.i = v; return c.f;
}
__device__ __forceinline__ float sigmoidf_(float v) { return 1.0f / (1.0f + expf(-v)); }
__device__ __forceinline__ unsigned short f2bf(float f) {
    unsigned int u = __float_as_uint(f);
    return (unsigned short)((u + 0x7fffu + ((u >> 16) & 1u)) >> 16);
}

extern "C" __global__ void pack_w(const float* __restrict__ Whh,
    const float* __restrict__ sWih, const float* __restrict__ sWhh,
    const float* __restrict__ Wq, const float* __restrict__ Wk, const float* __restrict__ Wv,
    const float* __restrict__ Wo, const float* __restrict__ Wp,
    const float* __restrict__ W_in, unsigned short* __restrict__ ws)
{
    unsigned e = blockIdx.x * 256u + threadIdx.x;
    if (e >= NPACK1) return;
    float v; bool isbf = false;
    if (e < OSUB) {
        unsigned idx = e >> 3, sl = e & 7u;
        unsigned jp = idx >> 8, t = idx & 255u, g = sl >> 1, ee = sl & 1u;
        v = Whh[(2u * jp + ee) * 1024u + g * 256u + t];
    } else if (e < OQK) {
        unsigned r = e - OSUB, idx = r >> 3, sl = r & 7u;
        unsigned q4 = idx & 3u, d = (idx >> 2) & 63u, jq = (idx >> 8) & 15u, s = idx >> 12;
        unsigned g = sl >> 1, ee = sl & 1u;
        unsigned j = jq * 4u + (q4 & 1u) * 2u + ee;
        const float* src = (q4 >> 1) ? sWhh : sWih;
        v = src[(s * 64u + j) * 256u + g * 64u + d];
    } else if (e < OV) {
        unsigned r = e - OQK, idx = r >> 3, sl = r & 7u;
        unsigned d = idx & 63u, jq = idx >> 6;
        unsigned j = jq * 4u + (sl & 3u);
        v = ((sl >> 2) ? Wk : Wq)[j * 64u + d];
    } else if (e < OWO) {
        unsigned r = e - OV, idx = r >> 3, sl = r & 7u;
        unsigned d = idx & 63u, jq2 = idx >> 6;
        unsigned j = jq2 * 8u + sl;
        v = Wv[j * 64u + d];
    } else if (e < OWP) {
        unsigned r = e - OWO, idx = r >> 3, sl = r & 7u;
        unsigned t = idx & 255u, jq2 = idx >> 8;
        unsigned j = jq2 * 8u + sl;
        v = Wo[j * 256u + t];
    } else if (e < OWIN) {
        unsigned r = e - OWP, idx = r >> 3, sl = r & 7u;
        unsigned t = idx & 255u, jq2 = idx >> 8;
        unsigned j = jq2 * 8u + sl;
        v = Wp[j * 256u + t];
    } else {
        v = W_in[e - OWIN]; isbf = true;
    }
    if (isbf) ws[e] = f2bf(v);
    else { union { __fp16 h; unsigned short s; } c; c.h = (__fp16)v; ws[e] = c.s; }
}

extern "C" __global__ void compute_wc(const float* __restrict__ W_in,
    const float* __restrict__ Wih, const float* __restrict__ b_in,
    const float* __restrict__ bih, unsigned short* __restrict__ ws)
{
    unsigned e = blockIdx.x * 256u + threadIdx.x;
    if (e < 131072u) {
        unsigned k = e >> 10, n = e & 1023u;
        float acc = 0.f;
        for (int j = 0; j < 256; ++j) acc += W_in[k * 256 + j] * Wih[j * 1024 + n];
        unsigned t = n & 255u, g = n >> 8;
        ws[OWC + k * 1024 + t * 4 + g] = f2bf(acc);
    } else if (e < 132096u) {
        unsigned n = e - 131072u;
        float acc = bih[n];
        for (int j = 0; j < 256; ++j) acc += b_in[j] * Wih[j * 1024 + n];
        float* bc = (float*)(ws + OBC);
        bc[n] = acc;
    }
}

extern "C" __global__ __launch_bounds__(512)
void xlstm_seq(const float* __restrict__ x, const float* __restrict__ b_in,
               const float* __restrict__ bq, const float* __restrict__ bk, const float* __restrict__ bv,
               const float* __restrict__ Wi, const float* __restrict__ bi,
               const float* __restrict__ Wf, const float* __restrict__ bf,
               const float* __restrict__ bo, const float* __restrict__ bp,
               const float* __restrict__ sbih, const float* __restrict__ sfb,
               const float* __restrict__ aW1, const float* __restrict__ ab1,
               const float* __restrict__ aW2, const float* __restrict__ ab2,
               const float* __restrict__ lng, const float* __restrict__ lnb,
               const unsigned short* __restrict__ pk,
               float* __restrict__ out)
{
    const int u = threadIdx.x;          // 0..511
    const int b = blockIdx.x;
    const int t256 = u & 255;
    const int half = u >> 8;

    __shared__ float g_chunk[CH][1024];
    __shared__ float xt_chunk[CH][256];
    __shared__ __align__(16) float xT[128][20];
    __shared__ __align__(16) float x1_l[256], hs_l[256];
    __shared__ float opre_l[256];
    __shared__ float psum[4][520];
    __shared__ float qb[64], kb[64], vb[64];
    __shared__ float Cm[64 * 65];
    __shared__ float sc_l[16];
    __shared__ __align__(16) float Wi_l[256], Wf_l[256];
    __shared__ float sbih_l[1024], bc_l[1024];
    __shared__ float b_in_l[256], bo_l[256], bp_l[256], sfb_l[256], bqkv_l[192];
    __shared__ __align__(16) unsigned int h0p[128], x1p[128], x2p[128], hsp[128], htp[32];

    // ---- init ----
    {
        const float* bcg = (const float*)(pk + OBC);
        for (int e = u; e < 1024; e += 512) { sbih_l[e] = sbih[e]; bc_l[e] = bcg[e]; }
    }
    if (u < 256) {
        Wi_l[u] = Wi[u]; Wf_l[u] = Wf[u];
        b_in_l[u] = b_in[u]; bo_l[u] = bo[u]; bp_l[u] = bp[u]; sfb_l[u] = sfb[u];
        hs_l[u] = 0.f;
    }
    if (u < 192) bqkv_l[u] = (u < 64) ? bq[u] : (u < 128) ? bk[u - 64] : bv[u - 128];
    if (u < 128) { h0p[u] = 0u; hsp[u] = 0u; }
    if (u == 0) { sc_l[10] = bi[0]; sc_l[11] = bf[0]; }
    for (int e = u; e < 64 * 65; e += 512) Cm[e] = 0.f;
    float c0 = 0.f, n0 = 1.f, cs = 0.f, ns = 1.f, n1 = 1.f;
    __syncthreads();

    const uint4* pwhh = reinterpret_cast<const uint4*>(pk + OHH) + t256;        // + jp*256
    const uint4* psub = reinterpret_cast<const uint4*>(pk + OSUB)
                        + ((size_t)((t256 >> 6) * 1024 + (t256 & 63))) * 4;     // + jq*256
    const uint4* pqk = reinterpret_cast<const uint4*>(pk + OQK) + (u & 63);     // + jq*64
    const uint4* pv4 = reinterpret_cast<const uint4*>(pk + OV) + (u & 63);      // + jq2*64
    const uint4* pwo = reinterpret_cast<const uint4*>(pk + OWO) + t256;         // + jq2*256
    const uint4* pwp = reinterpret_cast<const uint4*>(pk + OWP) + t256;         // + jq2*256
    const unsigned short* pwin = pk + OWIN + t256;
    const uint2* pwc = reinterpret_cast<const uint2*>(pk + OWC) + t256;
    const float* xrow = x + (size_t)b * TSTEPS * 128;

    for (int cc = 0; cc < NCHUNK; ++cc) {
        // ---- Phase A: load x chunk, transpose ----
        {
            float4 xv4 = *reinterpret_cast<const float4*>(xrow + cc * (CH * 128) + u * 4);
            int m = u >> 5, k0 = (u * 4) & 127;
            xT[k0][m] = xv4.x; xT[k0 + 1][m] = xv4.y; xT[k0 + 2][m] = xv4.z; xT[k0 + 3][m] = xv4.w;
        }
        __syncthreads();

        // ---- Phase B: xt = x@W_in + b_in ; g_ih = x@Wc + bc ----
        {
            const int m0 = half * 8;
            float xtacc[8], gacc[4][8];
            {
                float bi_ = b_in_l[t256];
                #pragma unroll
                for (int e = 0; e < 8; ++e) xtacc[e] = bi_;
                #pragma unroll
                for (int g = 0; g < 4; ++g) {
                    float bcv = bc_l[g * 256 + t256];
                    #pragma unroll
                    for (int e = 0; e < 8; ++e) gacc[g][e] = bcv;
                }
            }
            #pragma unroll 4
            for (int k = 0; k < 128; ++k) {
                float wv = bfu((unsigned)pwin[k * 256] << 16);
                uint2 wg = pwc[k * 256];
                float w0 = bfu(wg.x << 16), w1 = bfu(wg.x & 0xffff0000u);
                float w2 = bfu(wg.y << 16), w3 = bfu(wg.y & 0xffff0000u);
                float4 a  = *reinterpret_cast<const float4*>(&xT[k][m0]);
                float4 b4 = *reinterpret_cast<const float4*>(&xT[k][m0 + 4]);
                #pragma unroll
                for (int e = 0; e < 8; ++e) {
                    float xv = (e == 0) ? a.x : (e == 1) ? a.y : (e == 2) ? a.z : (e == 3) ? a.w
                             : (e == 4) ? b4.x : (e == 5) ? b4.y : (e == 6) ? b4.z : b4.w;
                    xtacc[e]   += xv * wv;
                    gacc[0][e] += xv * w0;
                    gacc[1][e] += xv * w1;
                    gacc[2][e] += xv * w2;
                    gacc[3][e] += xv * w3;
                }
            }
            #pragma unroll
            for (int e = 0; e < 8; ++e) {
                xt_chunk[m0 + e][t256] = xtacc[e];
                g_chunk[m0 + e][t256]       = gacc[0][e];
                g_chunk[m0 + e][256 + t256] = gacc[1][e];
                g_chunk[m0 + e][512 + t256] = gacc[2][e];
                g_chunk[m0 + e][768 + t256] = gacc[3][e];
            }
        }
        __syncthreads();

        for (int st = 0; st < CH; ++st) {
            // ---- S3: hh-half of layer-0 gates via fdot2 (split-K 2) ----
            {
                float g0 = 0.f, g1 = 0.f, g2 = 0.f, g3 = 0.f;
                const int jp0 = half * 64;
                #pragma unroll 4
                for (int q = 0; q < 16; ++q) {
                    uint4 hp4 = *reinterpret_cast<const uint4*>(&h0p[jp0 + q * 4]);
                    #pragma unroll
                    for (int e = 0; e < 4; ++e) {
                        uint4 wk = pwhh[(size_t)(jp0 + q * 4 + e) * 256];
                        unsigned int hp = (e == 0) ? hp4.x : (e == 1) ? hp4.y : (e == 2) ? hp4.z : hp4.w;
                        g0 = dot2(wk.x, hp, g0);
                        g1 = dot2(wk.y, hp, g1);
                        g2 = dot2(wk.z, hp, g2);
                        g3 = dot2(wk.w, hp, g3);
                    }
                }
                psum[0][u] = g0; psum[1][u] = g1; psum[2][u] = g2; psum[3][u] = g3;
            }
            __syncthreads();
            if (u < 256) {
                float G0 = g_chunk[st][u]       + psum[0][u] + psum[0][256 + u];
                float G1 = g_chunk[st][256 + u] + psum[1][u] + psum[1][256 + u];
                float G2 = g_chunk[st][512 + u] + psum[2][u] + psum[2][256 + u];
                float G3 = g_chunk[st][768 + u] + psum[3][u] + psum[3][256 + u];
                float i0 = expf(G0), f0 = sigmoidf_(G1), o0 = sigmoidf_(G2);
                float cn = f0 * c0 + i0 * tanhf(G3);
                float nn = f0 * n0 + i0;
                c0 = cn; n0 = nn;
                float h0n = o0 * tanhf(cn / (nn + EPSR));
                float x1v = h0n + xt_chunk[st][u];
                x1_l[u] = x1v;
                float h0o = __shfl_xor(h0n, 1);
                float x1o = __shfl_xor(x1v, 1);
                if (!(u & 1)) { h0p[u >> 1] = pk2f(h0n, h0o); x1p[u >> 1] = pk2f(x1v, x1o); }
            }
            __syncthreads();

            // ---- S4: qkv via fdot2 (split-K 4, V widened to uint4) | i/f dots ----
            if (u < 256) {
                const int jq0 = (u >> 6) * 16;      // 16 jq's = 8 jq2's
                float pq = 0.f, pkk = 0.f, pvv = 0.f;
                #pragma unroll 4
                for (int q2 = 0; q2 < 8; ++q2) {
                    int jq = jq0 + q2 * 2;
                    uint4 wqk0 = pqk[(size_t)jq * 64];
                    uint4 wqk1 = pqk[(size_t)(jq + 1) * 64];
                    uint4 wv4 = pv4[(size_t)((jq0 >> 1) + q2) * 64];
                    uint4 ap4 = *reinterpret_cast<const uint4*>(&x1p[jq * 2]);
                    pq  = dot2(wqk0.x, ap4.x, pq);  pq  = dot2(wqk0.y, ap4.y, pq);
                    pq  = dot2(wqk1.x, ap4.z, pq);  pq  = dot2(wqk1.y, ap4.w, pq);
                    pkk = dot2(wqk0.z, ap4.x, pkk); pkk = dot2(wqk0.w, ap4.y, pkk);
                    pkk = dot2(wqk1.z, ap4.z, pkk); pkk = dot2(wqk1.w, ap4.w, pkk);
                    pvv = dot2(wv4.x, ap4.x, pvv);  pvv = dot2(wv4.y, ap4.y, pvv);
                    pvv = dot2(wv4.z, ap4.z, pvv);  pvv = dot2(wv4.w, ap4.w, pvv);
                }
                psum[0][u] = pq; psum[1][u] = pkk; psum[2][u] = pvv;
            } else if (u < 384) {
                const float* Wl = (u < 320) ? Wi_l : Wf_l;
                int j0 = (u & 63) * 4;
                float4 xv = *reinterpret_cast<const float4*>(&x1_l[j0]);
                float4 wv = *reinterpret_cast<const float4*>(&Wl[j0]);
                float p = xv.x * wv.x + xv.y * wv.y + xv.z * wv.z + xv.w * wv.w;
                #pragma unroll
                for (int off = 32; off > 0; off >>= 1) p += __shfl_down(p, off);
                if ((u & 63) == 0) sc_l[(u < 320) ? 8 : 9] = p;
            }
            __syncthreads();
            {
                int lane = u & 63;
                if (u < 64)        qb[u]    = bqkv_l[u]          + psum[0][u] + psum[0][64 + u] + psum[0][128 + u] + psum[0][192 + u];
                else if (u < 128)  kb[lane] = bqkv_l[64 + lane]  + psum[1][lane] + psum[1][64 + lane] + psum[1][128 + lane] + psum[1][192 + lane];
                else if (u < 192)  vb[lane] = bqkv_l[128 + lane] + psum[2][lane] + psum[2][64 + lane] + psum[2][128 + lane] + psum[2][192 + lane];
                else if (u == 192) sc_l[0] = expf(sc_l[10] + sc_l[8]);
                else if (u == 193) sc_l[1] = sigmoidf_(sc_l[11] + sc_l[9]);
            }
            __syncthreads();

            // ---- S5: C update + fused Cq + htp pack + Wo via fdot2 (uint4) ----
            float i1 = sc_l[0], f1 = sc_l[1];
            n1 = f1 * n1 + i1;
            {
                int r = u >> 3, ci = (u & 7) * 8;
                float vi = i1 * vb[r];
                float cqp = 0.f;
                #pragma unroll
                for (int e = 0; e < 8; ++e) {
                    int c = ci + e;
                    float cmv = f1 * Cm[r * 65 + c] + vi * kb[c];
                    Cm[r * 65 + c] = cmv;
                    cqp += cmv * qb[c];
                }
                cqp += __shfl_down(cqp, 4);
                cqp += __shfl_down(cqp, 2);
                cqp += __shfl_down(cqp, 1);
                float htv = cqp / (n1 + EPSR);
                float hto = __shfl_xor(htv, 8);
                if ((u & 15) == 0) htp[u >> 4] = pk2f(htv, hto);

                float p = 0.f;
                const int jq20 = half * 16;          // 16 uint4 loads cover jq = half*32..+31
                #pragma unroll 4
                for (int q2 = 0; q2 < 16; ++q2) {
                    uint4 w4 = pwo[(size_t)(jq20 + q2) * 256];
                    int jq = (jq20 + q2) * 2;
                    uint4 ap4 = *reinterpret_cast<const uint4*>(&x1p[jq * 2]);
                    p = dot2(w4.x, ap4.x, p); p = dot2(w4.y, ap4.y, p);
                    p = dot2(w4.z, ap4.z, p); p = dot2(w4.w, ap4.w, p);
                }
                psum[3][u] = p;
            }
            __syncthreads();

            // ---- S6: opre combine + Wp via fdot2 (uint4) ----
            {
                if (u < 256) opre_l[u] = bo_l[u] + psum[3][u] + psum[3][256 + u];
                float p = 0.f;
                const int jq20 = half * 4;           // 4 uint4 loads cover jq = half*8..+7
                #pragma unroll
                for (int q2 = 0; q2 < 4; ++q2) {
                    uint4 w4 = pwp[(size_t)(jq20 + q2) * 256];
                    int jq = (jq20 + q2) * 2;
                    uint4 ap4 = *reinterpret_cast<const uint4*>(&htp[jq * 2]);
                    p = dot2(w4.x, ap4.x, p); p = dot2(w4.y, ap4.y, p);
                    p = dot2(w4.z, ap4.z, p); p = dot2(w4.w, ap4.w, p);
                }
                psum[0][u] = p;
            }
            __syncthreads();
            if (u < 256) {
                float pp = bp_l[u] + psum[0][u] + psum[0][256 + u];
                float h1 = sigmoidf_(opre_l[u]) * tanhf(pp);
                float x2v = h1 + x1_l[u];
                float x2o = __shfl_xor(x2v, 1);
                if (!(u & 1)) x2p[u >> 1] = pk2f(x2v, x2o);
            }
            __syncthreads();

            // ---- S8: subspace gates via fdot2 (split-K 2) ----
            {
                const int sbase = (t256 >> 6) * 32;
                const int jqb = half * 8;
                float g0 = 0.f, g1 = 0.f, g2 = 0.f, g3 = 0.f;
                #pragma unroll 2
                for (int q = 0; q < 8; ++q) {
                    int jq = jqb + q;
                    const uint4* pp4 = psub + (size_t)jq * 256;
                    uint4 wih0 = pp4[0], wih1 = pp4[1], whh0 = pp4[2], whh1 = pp4[3];
                    uint2 xp = *reinterpret_cast<const uint2*>(&x2p[sbase + jq * 2]);
                    uint2 hp = *reinterpret_cast<const uint2*>(&hsp[sbase + jq * 2]);
                    g0 = dot2(wih0.x, xp.x, g0); g0 = dot2(wih1.x, xp.y, g0);
                    g0 = dot2(whh0.x, hp.x, g0); g0 = dot2(whh1.x, hp.y, g0);
                    g1 = dot2(wih0.y, xp.x, g1); g1 = dot2(wih1.y, xp.y, g1);
                    g1 = dot2(whh0.y, hp.x, g1); g1 = dot2(whh1.y, hp.y, g1);
                    g2 = dot2(wih0.z, xp.x, g2); g2 = dot2(wih1.z, xp.y, g2);
                    g2 = dot2(whh0.z, hp.x, g2); g2 = dot2(whh1.z, hp.y, g2);
                    g3 = dot2(wih0.w, xp.x, g3); g3 = dot2(wih1.w, xp.y, g3);
                    g3 = dot2(whh0.w, hp.x, g3); g3 = dot2(whh1.w, hp.y, g3);
                }
                psum[0][u] = g0; psum[1][u] = g1; psum[2][u] = g2; psum[3][u] = g3;
            }
            __syncthreads();
            if (u < 256) {
                int s = u >> 6, dd = u & 63;
                float sg0 = psum[0][u] + psum[0][256 + u] + sbih_l[s * 256 + dd];
                float sg1 = psum[1][u] + psum[1][256 + u] + sbih_l[s * 256 + 64 + dd];
                float sg2 = psum[2][u] + psum[2][256 + u] + sbih_l[s * 256 + 128 + dd];
                float sg3 = psum[3][u] + psum[3][256 + u] + sbih_l[s * 256 + 192 + dd];
                float si = expf(sg0);
                float sf = sigmoidf_(sg1 + sfb_l[u]);
                float so = sigmoidf_(sg2);
                float csn = sf * cs + si * tanhf(sg3);
                float nsn = sf * ns + si;
                cs = csn; ns = nsn;
                float hsn = so * tanhf(csn / (nsn + EPSR));
                hs_l[u] = hsn;
                float hso = __shfl_xor(hsn, 1);
                if (!(u & 1)) hsp[u >> 1] = pk2f(hsn, hso);
            }
            __syncthreads();
        }
    }

    // ---- epilogue: attention fusion + layernorm ----
    if (u < 256) {
        int s = u >> 6, dd = u & 63;
        float av = ab1[dd];
        for (int j = 0; j < 64; ++j) av += hs_l[s * 64 + j] * aW1[j * 64 + dd];
        float contrib = tanhf(av) * aW2[dd];
        #pragma unroll
        for (int off = 32; off > 0; off >>= 1) contrib += __shfl_down(contrib, off);
        if (dd == 0) sc_l[4 + s] = contrib + ab2[0];
    }
    __syncthreads();
    if (u < 256) {
        float a0 = sc_l[4], a1 = sc_l[5], a2 = sc_l[6], a3 = sc_l[7];
        float m = fmaxf(fmaxf(a0, a1), fmaxf(a2, a3));
        float e0 = expf(a0 - m), e1 = expf(a1 - m), e2 = expf(a2 - m), e3 = expf(a3 - m);
        float inv = 1.f / (e0 + e1 + e2 + e3);
        int dd = u & 63;
        psum[0][u] = (e0 * hs_l[dd] + e1 * hs_l[64 + dd] + e2 * hs_l[128 + dd] + e3 * hs_l[192 + dd]) * inv;
    }
    __syncthreads();
    if (u < 256) {
        float mu = 0.f;
        for (int j = 0; j < 256; ++j) mu += psum[0][j];
        mu *= (1.0f / 256.0f);
        float var = 0.f;
        for (int j = 0; j < 256; ++j) { float dv = psum[0][j] - mu; var += dv * dv; }
        var *= (1.0f / 256.0f);
        out[b * 256 + u] = (psum[0][u] - mu) / sqrtf(var + 1e-5f) * lng[u] + lnb[u];
    }
}

extern "C" void kernel_launch(void* const* d_in, const int* in_sizes, int n_in,
                              void* d_out, int out_size, void* d_ws, size_t ws_size,
                              hipStream_t stream) {
    (void)in_sizes; (void)n_in; (void)out_size; (void)ws_size;
    const float* x     = (const float*)d_in[0];
    const float* W_in  = (const float*)d_in[1];
    const float* b_in  = (const float*)d_in[2];
    const float* Wih   = (const float*)d_in[3];
    const float* bih   = (const float*)d_in[4];
    const float* Whh   = (const float*)d_in[5];
    const float* Wq    = (const float*)d_in[6];
    const float* bq    = (const float*)d_in[7];
    const float* Wk    = (const float*)d_in[8];
    const float* bk    = (const float*)d_in[9];
    const float* Wv    = (const float*)d_in[10];
    const float* bv    = (const float*)d_in[11];
    const float* Wi    = (const float*)d_in[12];
    const float* bi    = (const float*)d_in[13];
    const float* Wf    = (const float*)d_in[14];
    const float* bf    = (const float*)d_in[15];
    const float* Wo    = (const float*)d_in[16];
    const float* bo    = (const float*)d_in[17];
    const float* Wp    = (const float*)d_in[18];
    const float* bp    = (const float*)d_in[19];
    const float* sWih  = (const float*)d_in[20];
    const float* sbih  = (const float*)d_in[21];
    const float* sWhh  = (const float*)d_in[22];
    const float* sfb   = (const float*)d_in[23];
    const float* aW1   = (const float*)d_in[24];
    const float* ab1   = (const float*)d_in[25];
    const float* aW2   = (const float*)d_in[26];
    const float* ab2   = (const float*)d_in[27];
    const float* lng   = (const float*)d_in[28];
    const float* lnb   = (const float*)d_in[29];
    float* out = (float*)d_out;
    unsigned short* ws = (unsigned short*)d_ws;

    pack_w<<<dim3((NPACK1 + 255u) / 256u), dim3(256), 0, stream>>>(
        Whh, sWih, sWhh, Wq, Wk, Wv, Wo, Wp, W_in, ws);
    compute_wc<<<dim3(517), dim3(256), 0, stream>>>(W_in, Wih, b_in, bih, ws);

    xlstm_seq<<<dim3(256), dim3(512), 0, stream>>>(
        x, b_in, bq, bk, bv, Wi, bi, Wf, bf, bo, bp,
        sbih, sfb, aW1, ab1, aW2, ab2, lng, lnb, ws, out);
}